// Round 1
// baseline (1721.174 us; speedup 1.0000x reference)
//
#include <hip/hip_runtime.h>

// SqRL ring gather, H = W = 512 (even), lmid = 255, Hr = 256, row width 4H = 2048.
// out[b,c,dif,j] = x[b,c, r(dif,j), c(dif,j)] with closed-form ring index map:
//   i  = 255 - dif, el = 2*dif + 1   (H even)
//   segment boundaries b0..b8 (b8 = 4H-4 = 2044), j in [2044,2048) wraps to j-2044.
//   seg0+1 (j <  b1): r=i,        c=max(j,i)
//   seg2+3 (j <  b3): c=511-i,    r=i + max(j-b2,0)
//   seg4+5 (j <  b5): r=i+el,     c=i+el - max(j-b4,0)     (note i+el == 511-i)
//   seg6+7 (j <  b7): c=i,        r=i+el - max(j-b6,0)
//   seg8   (j >= b7): r=i, c=i
// Verified against the python _build_ring_index construction for dif=0 and dif=255.

#define SQRL_H 512
#define SQRL_IMG ((size_t)SQRL_H * SQRL_H)   // 262144 elems per (b,c) image
#define SQRL_ROWW 2048                        // 4*H output row width
#define SQRL_NR 256                           // rings per image

__global__ __launch_bounds__(256) void sqrl_gather_kernel(
    const float* __restrict__ x, float4* __restrict__ out, long n4) {
    long t = (long)blockIdx.x * blockDim.x + threadIdx.x;
    if (t >= n4) return;

    int  j4  = (int)(t & 511);   // 512 float4 per output row
    long row = t >> 9;           // img*256 + dif
    int  dif = (int)(row & 255);
    long img = row >> 8;

    const float* __restrict__ base = x + img * SQRL_IMG;

    const int i_ = 255 - dif;
    const int el = 2 * dif + 1;
    const int b1 = i_ + el;          // == i+el == 511-i_
    const int b2 = b1 + 2 * i_;
    const int b3 = b2 + el;
    const int b4 = b3 + 2 * i_;
    const int b5 = b4 + el;
    const int b6 = b5 + 2 * i_;
    const int b7 = b6 + el;

    const int j0 = j4 * 4;
    float4 v;
    float* vp = reinterpret_cast<float*>(&v);
#pragma unroll
    for (int k = 0; k < 4; ++k) {
        int j  = j0 + k;
        int jj = (j >= 2044) ? (j - 2044) : j;   // tail wrap
        int r, c;
        if (jj < b1)      { r = i_;       c = (jj > i_) ? jj : i_; }
        else if (jj < b3) { c = 511 - i_; int d = jj - b2; r = i_ + (d > 0 ? d : 0); }
        else if (jj < b5) { r = b1;       int d = jj - b4; c = b1 - (d > 0 ? d : 0); }
        else if (jj < b7) { c = i_;       int d = jj - b6; r = b1 - (d > 0 ? d : 0); }
        else              { r = i_;       c = i_; }
        vp[k] = base[(size_t)r * SQRL_H + c];
    }
    out[t] = v;
}

extern "C" void kernel_launch(void* const* d_in, const int* in_sizes, int n_in,
                              void* d_out, int out_size, void* d_ws, size_t ws_size,
                              hipStream_t stream) {
    const float* x = (const float*)d_in[0];
    float4* out = (float4*)d_out;
    long n4 = (long)out_size / 4;            // 67,108,864 float4 outputs
    long nblocks = (n4 + 255) / 256;         // 262,144 blocks
    sqrl_gather_kernel<<<dim3((unsigned)nblocks), dim3(256), 0, stream>>>(x, out, n4);
}